// Round 2
// baseline (3711.604 us; speedup 1.0000x reference)
//
#include <hip/hip_runtime.h>

constexpr int B_ = 4, C_ = 16, H_ = 512, W_ = 512;
constexpr int HW = H_ * W_;            // 262144 = 1<<18
constexpr float EPSF = 1e-10f;

// ---------------- scatter, channel-last accumulator ----------------
// A layout: [b][cell(r*W+cc)][c]  (16 consecutive floats per cell)
__global__ __launch_bounds__(256) void scatter_cl(const float* __restrict__ x,
                                                  const float* __restrict__ grid,
                                                  float* __restrict__ A,
                                                  float* __restrict__ D) {
  int tid = blockIdx.x * 256 + threadIdx.x;   // over B*H*W
  int b  = tid >> 18;
  int ij = tid & (HW - 1);

  float2 g = ((const float2*)grid)[tid];
  float gi = (g.x + 1.0f) * 0.5f * (float)H_ + 1.0f;
  float gj = (g.y + 1.0f) * 0.5f * (float)W_ + 1.0f;
  gi = fminf(fmaxf(gi, 0.0f), (float)(H_ + 1 - 2e-10));   // == 513.0f, matches ref fp32
  gj = fminf(fmaxf(gj, 0.0f), (float)(W_ + 1 - 2e-10));
  int ii0 = (int)gi, jj0 = (int)gj;
  float fi = gi - (float)ii0, fj = gj - (float)jj0;       // exact (Sterbenz)
  float wi[2] = {1.0f - fi, fi};
  float wj[2] = {1.0f - fj, fj};

  // load all 16 channels (coalesced per c across lanes)
  float xv[16];
  const float* xb = x + (((size_t)b * C_) << 18) + ij;
  #pragma unroll
  for (int c = 0; c < 16; ++c) xv[c] = xb[(size_t)c << 18];

  #pragma unroll
  for (int di = 0; di < 2; ++di) {
    int r = ii0 + di - 1;                       // cropped output row
    if ((unsigned)r >= (unsigned)H_) continue;
    #pragma unroll
    for (int dj = 0; dj < 2; ++dj) {
      int cc = jj0 + dj - 1;
      if ((unsigned)cc >= (unsigned)W_) continue;
      float wgt = wi[di] * wj[dj];
      int cell = (b << 18) + (r << 9) + cc;
      unsafeAtomicAdd(D + cell, wgt);
      float* Ab = A + ((size_t)cell << 4);
      #pragma unroll
      for (int c = 0; c < 16; ++c)
        unsafeAtomicAdd(Ab + c, xv[c] * wgt);
    }
  }
}

// ---------------- normalize + transpose (channel-last -> BCHW) ----------------
__global__ __launch_bounds__(256) void norm_transpose(const float* __restrict__ A,
                                                      const float* __restrict__ D,
                                                      float* __restrict__ out) {
  __shared__ float tile[64 * 17];
  __shared__ float dv[64];
  int t = threadIdx.x;
  int cellBase = blockIdx.x << 6;               // 64 cells per block

  // coalesced read: 1024 floats = 4/thread
  float4 v = ((const float4*)A)[(((size_t)cellBase) << 2) + t];
  int e = t << 2;
  int cell = e >> 4;           // t>>2
  int c0 = e & 15;
  tile[cell * 17 + c0 + 0] = v.x;
  tile[cell * 17 + c0 + 1] = v.y;
  tile[cell * 17 + c0 + 2] = v.z;
  tile[cell * 17 + c0 + 3] = v.w;
  if (t < 64) dv[t] = D[cellBase + t];
  __syncthreads();

  int b   = cellBase >> 18;
  int rem = cellBase & (HW - 1);               // r*W + cc0 (cc0 multiple of 64)
  #pragma unroll
  for (int k = 0; k < 4; ++k) {
    int o = t + (k << 8);
    int c  = o >> 6;
    int ce = o & 63;
    float a  = tile[ce * 17 + c];              // stride 17 -> conflict-free (2-way)
    float Dv = dv[ce];
    float val = (Dv > EPSF) ? (a / (Dv + EPSF)) : 1.0f;
    out[(((size_t)(b * C_ + c)) << 18) + rem + ce] = val;
  }
}

// ---------------- fallback path (small ws): atomics straight into out ----------------
__global__ __launch_bounds__(256) void scatter_direct(const float* __restrict__ x,
                                                      const float* __restrict__ grid,
                                                      float* __restrict__ out,
                                                      float* __restrict__ D) {
  int tid = blockIdx.x * 256 + threadIdx.x;
  int b  = tid >> 18;
  int ij = tid & (HW - 1);
  float2 g = ((const float2*)grid)[tid];
  float gi = (g.x + 1.0f) * 0.5f * (float)H_ + 1.0f;
  float gj = (g.y + 1.0f) * 0.5f * (float)W_ + 1.0f;
  gi = fminf(fmaxf(gi, 0.0f), (float)(H_ + 1 - 2e-10));
  gj = fminf(fmaxf(gj, 0.0f), (float)(W_ + 1 - 2e-10));
  int ii0 = (int)gi, jj0 = (int)gj;
  float fi = gi - (float)ii0, fj = gj - (float)jj0;
  float wi[2] = {1.0f - fi, fi};
  float wj[2] = {1.0f - fj, fj};
  float xv[16];
  const float* xb = x + (((size_t)b * C_) << 18) + ij;
  #pragma unroll
  for (int c = 0; c < 16; ++c) xv[c] = xb[(size_t)c << 18];
  #pragma unroll
  for (int di = 0; di < 2; ++di) {
    int r = ii0 + di - 1;
    if ((unsigned)r >= (unsigned)H_) continue;
    #pragma unroll
    for (int dj = 0; dj < 2; ++dj) {
      int cc = jj0 + dj - 1;
      if ((unsigned)cc >= (unsigned)W_) continue;
      float wgt = wi[di] * wj[dj];
      int rcc = (r << 9) + cc;
      unsafeAtomicAdd(D + (b << 18) + rcc, wgt);
      #pragma unroll
      for (int c = 0; c < 16; ++c)
        unsafeAtomicAdd(out + (((size_t)(b * C_ + c)) << 18) + rcc, xv[c] * wgt);
    }
  }
}

__global__ __launch_bounds__(256) void norm_direct(float* __restrict__ out,
                                                   const float* __restrict__ D) {
  int n4 = B_ * C_ * HW / 4;
  int stride = gridDim.x * blockDim.x;
  for (int i4 = blockIdx.x * blockDim.x + threadIdx.x; i4 < n4; i4 += stride) {
    int base = i4 << 2;
    int b   = base >> 22;                      // /(C_*HW)
    int rem = base & (HW - 1);
    float4 a  = ((float4*)out)[i4];
    float4 dv = ((const float4*)D)[((b << 18) + rem) >> 2];
    float4 r;
    r.x = (dv.x > EPSF) ? (a.x / (dv.x + EPSF)) : 1.0f;
    r.y = (dv.y > EPSF) ? (a.y / (dv.y + EPSF)) : 1.0f;
    r.z = (dv.z > EPSF) ? (a.z / (dv.z + EPSF)) : 1.0f;
    r.w = (dv.w > EPSF) ? (a.w / (dv.w + EPSF)) : 1.0f;
    ((float4*)out)[i4] = r;
  }
}

extern "C" void kernel_launch(void* const* d_in, const int* in_sizes, int n_in,
                              void* d_out, int out_size, void* d_ws, size_t ws_size,
                              hipStream_t stream) {
  const float* x    = (const float*)d_in[0];
  const float* grid = (const float*)d_in[1];
  float* out = (float*)d_out;

  const size_t needD = (size_t)B_ * HW * sizeof(float);        // 4 MiB
  const size_t needA = (size_t)B_ * HW * C_ * sizeof(float);   // 64 MiB

  float* D = (float*)d_ws;
  if (ws_size >= needD + needA) {
    float* A = (float*)((char*)d_ws + needD);
    hipMemsetAsync(d_ws, 0, needD + needA, stream);
    scatter_cl<<<B_ * HW / 256, 256, 0, stream>>>(x, grid, A, D);
    norm_transpose<<<B_ * HW / 64, 256, 0, stream>>>(A, D, out);
  } else {
    // fallback: accumulate directly into out (BCHW), D in ws
    hipMemsetAsync(out, 0, (size_t)B_ * C_ * HW * sizeof(float), stream);
    hipMemsetAsync(D, 0, needD, stream);
    scatter_direct<<<B_ * HW / 256, 256, 0, stream>>>(x, grid, out, D);
    norm_direct<<<2048, 256, 0, stream>>>(out, D);
  }
}

// Round 3
// 742.053 us; speedup vs baseline: 5.0018x; 5.0018x over previous
//
#include <hip/hip_runtime.h>

constexpr int B_ = 4, C_ = 16, H_ = 512, W_ = 512;
constexpr int HW = H_ * W_;            // 1<<18
constexpr int NPTS = B_ * HW;          // 1<<20
constexpr float EPSF = 1e-10f;

// tiles: 16 rows x 32 cols of output cells
constexpr int TRL2 = 4, TCL2 = 5;
constexpr int TROWS = H_ >> TRL2;      // 32 tile-rows
constexpr int TCOLS = W_ >> TCL2;      // 16 tile-cols
constexpr int NBIN  = B_ * TROWS * TCOLS;  // 2048
constexpr int CELLS = (1 << TRL2) * (1 << TCL2);  // 512 cells/tile
constexpr int CAP   = 3 << 19;         // 1.57M records (expected ~1.1M)

// ---- shared coordinate math (must be identical in hist/scatter/accum) ----
__device__ __forceinline__ void coords(float2 g, float& gi, float& gj, int& ii0, int& jj0) {
  gi = fminf(fmaxf((g.x + 1.0f) * 0.5f * (float)H_ + 1.0f, 0.0f), (float)(H_ + 1 - 2e-10));
  gj = fminf(fmaxf((g.y + 1.0f) * 0.5f * (float)W_ + 1.0f, 0.0f), (float)(W_ + 1 - 2e-10));
  ii0 = (int)gi; jj0 = (int)gj;
}
// candidate tile rows for footprint rows {ii0-1, ii0}; branchless, no arrays
__device__ __forceinline__ void tileR(int ii0, int& t0, int& t1, bool& v0, bool& v1) {
  int r0 = ii0 - 1, r1 = ii0;
  bool a = (unsigned)r0 < (unsigned)H_;
  bool b = (unsigned)r1 < (unsigned)H_;
  t0 = (a ? r0 : r1) >> TRL2;
  t1 = r1 >> TRL2;
  v0 = a | b;
  v1 = a & b & ((r1 >> TRL2) != (r0 >> TRL2));
}
__device__ __forceinline__ void tileC(int jj0, int& t0, int& t1, bool& v0, bool& v1) {
  int c0 = jj0 - 1, c1 = jj0;
  bool a = (unsigned)c0 < (unsigned)W_;
  bool b = (unsigned)c1 < (unsigned)W_;
  t0 = (a ? c0 : c1) >> TCL2;
  t1 = c1 >> TCL2;
  v0 = a | b;
  v1 = a & b & ((c1 >> TCL2) != (c0 >> TCL2));
}
__device__ __forceinline__ int binOf(int b, int tr, int tc) {
  return (b * TROWS + tr) * TCOLS + tc;
}

// ---- K0: BCHW -> channel-last x_cl[point][16] ----
__global__ __launch_bounds__(256) void transpose_cl(const float* __restrict__ x,
                                                    float* __restrict__ x_cl) {
  __shared__ float tile[64 * 17];
  int t = threadIdx.x;
  int cellBase = blockIdx.x << 6;          // 64 points per block
  int b   = cellBase >> 18;
  int ij0 = cellBase & (HW - 1);
  const float* xb = x + (((size_t)b * C_) << 18) + ij0;
  #pragma unroll
  for (int k = 0; k < 4; ++k) {
    int o = (k << 8) + t;
    int c = o >> 6, ce = o & 63;
    tile[ce * 17 + c] = xb[((size_t)c << 18) + ce];  // coalesced 256B per wave
  }
  __syncthreads();
  int cell = t >> 2, c0 = (t & 3) << 2;
  float4 v = { tile[cell * 17 + c0], tile[cell * 17 + c0 + 1],
               tile[cell * 17 + c0 + 2], tile[cell * 17 + c0 + 3] };
  ((float4*)x_cl)[(((size_t)cellBase) << 2) + t] = v;
}

// ---- K1: per-bin histogram (with duplication) ----
__global__ __launch_bounds__(256) void hist_kernel(const float2* __restrict__ grid,
                                                   int* __restrict__ hist) {
  __shared__ int h[NBIN];
  for (int i = threadIdx.x; i < NBIN; i += 256) h[i] = 0;
  __syncthreads();
  int stride = gridDim.x * 256;
  for (int tid = blockIdx.x * 256 + threadIdx.x; tid < NPTS; tid += stride) {
    int b = tid >> 18;
    float gi, gj; int ii0, jj0;
    coords(grid[tid], gi, gj, ii0, jj0);
    int tr0, tr1, tc0, tc1; bool vr0, vr1, vc0, vc1;
    tileR(ii0, tr0, tr1, vr0, vr1);
    tileC(jj0, tc0, tc1, vc0, vc1);
    if (vr0 & vc0) atomicAdd(&h[binOf(b, tr0, tc0)], 1);
    if (vr0 & vc1) atomicAdd(&h[binOf(b, tr0, tc1)], 1);
    if (vr1 & vc0) atomicAdd(&h[binOf(b, tr1, tc0)], 1);
    if (vr1 & vc1) atomicAdd(&h[binOf(b, tr1, tc1)], 1);
  }
  __syncthreads();
  for (int i = threadIdx.x; i < NBIN; i += 256) { int v = h[i]; if (v) atomicAdd(&hist[i], v); }
}

// ---- K2: exclusive scan of 2048 bins, one block ----
__global__ __launch_bounds__(256) void scan_bins(const int* __restrict__ hist,
                                                 int* __restrict__ offs,
                                                 int* __restrict__ cursor) {
  __shared__ int part[256];
  int t = threadIdx.x;
  int base = t * 8;
  int loc[8]; int s = 0;
  #pragma unroll
  for (int i = 0; i < 8; ++i) { loc[i] = s; s += hist[base + i]; }
  part[t] = s;
  __syncthreads();
  for (int d = 1; d < 256; d <<= 1) {
    int v = part[t];
    int u = (t >= d) ? part[t - d] : 0;
    __syncthreads();
    part[t] = v + u;
    __syncthreads();
  }
  int tex = (t == 0) ? 0 : part[t - 1];
  #pragma unroll
  for (int i = 0; i < 8; ++i) { int o = tex + loc[i]; offs[base + i] = o; cursor[base + i] = o; }
}

// ---- K3: scatter 16B records {gi, gj, id} into bin segments ----
__global__ __launch_bounds__(256) void scatter_recs(const float2* __restrict__ grid,
                                                    int* __restrict__ cursor,
                                                    float4* __restrict__ recs) {
  int tid = blockIdx.x * 256 + threadIdx.x;
  if (tid >= NPTS) return;
  int b = tid >> 18;
  float gi, gj; int ii0, jj0;
  coords(grid[tid], gi, gj, ii0, jj0);
  int tr0, tr1, tc0, tc1; bool vr0, vr1, vc0, vc1;
  tileR(ii0, tr0, tr1, vr0, vr1);
  tileC(jj0, tc0, tc1, vc0, vc1);
  float4 rec = { gi, gj, __int_as_float(tid), 0.0f };
  if (vr0 & vc0) { int p = atomicAdd(&cursor[binOf(b, tr0, tc0)], 1); if (p < CAP) recs[p] = rec; }
  if (vr0 & vc1) { int p = atomicAdd(&cursor[binOf(b, tr0, tc1)], 1); if (p < CAP) recs[p] = rec; }
  if (vr1 & vc0) { int p = atomicAdd(&cursor[binOf(b, tr1, tc0)], 1); if (p < CAP) recs[p] = rec; }
  if (vr1 & vc1) { int p = atomicAdd(&cursor[binOf(b, tr1, tc1)], 1); if (p < CAP) recs[p] = rec; }
}

// ---- K4: per-tile LDS accumulate + normalize + BCHW write ----
__global__ __launch_bounds__(256) void accum_bins(const float4* __restrict__ recs,
                                                  const int* __restrict__ offs,
                                                  const int* __restrict__ hist,
                                                  const float* __restrict__ x_cl,
                                                  float* __restrict__ out) {
  __shared__ float Af[C_ * CELLS];   // channel-major planes: [c][cell], 32 KB
  __shared__ float Df[CELLS];        // 2 KB
  int t = threadIdx.x;
  int bin = blockIdx.x;
  for (int i = t; i < C_ * CELLS; i += 256) Af[i] = 0.0f;
  for (int i = t; i < CELLS; i += 256) Df[i] = 0.0f;
  __syncthreads();

  int b   = bin >> 9;
  int trv = (bin >> 4) & 31, tcv = bin & 15;
  int row0 = trv << TRL2, col0 = tcv << TCL2;
  int start = offs[bin], cnt = hist[bin];

  for (int p = start + t; p < start + cnt; p += 256) {
    float4 rec = recs[p];
    float gi = rec.x, gj = rec.y;
    int id = __float_as_int(rec.z);
    int ii0 = (int)gi, jj0 = (int)gj;
    float fi = gi - (float)ii0, fj = gj - (float)jj0;
    float wr[2] = {1.0f - fi, fi};
    float wc[2] = {1.0f - fj, fj};
    const float4* xp = (const float4*)(x_cl + ((size_t)id << 4));
    float4 a0 = xp[0], a1 = xp[1], a2 = xp[2], a3 = xp[3];
    float xv[16] = { a0.x, a0.y, a0.z, a0.w, a1.x, a1.y, a1.z, a1.w,
                     a2.x, a2.y, a2.z, a2.w, a3.x, a3.y, a3.z, a3.w };
    #pragma unroll
    for (int di = 0; di < 2; ++di) {
      int r = ii0 - 1 + di;
      unsigned lr = (unsigned)(r - row0);
      if (lr >= (unsigned)(1 << TRL2)) continue;
      #pragma unroll
      for (int dj = 0; dj < 2; ++dj) {
        int cc = jj0 - 1 + dj;
        unsigned lc = (unsigned)(cc - col0);
        if (lc >= (unsigned)(1 << TCL2)) continue;
        float w = wr[di] * wc[dj];
        int cell = (int)(lr << TCL2) + (int)lc;
        atomicAdd(&Df[cell], w);
        #pragma unroll
        for (int c = 0; c < 16; ++c)
          atomicAdd(&Af[c * CELLS + cell], xv[c] * w);   // random banks per lane
      }
    }
  }
  __syncthreads();

  size_t obase = ((size_t)b) << 22;   // b * C * HW
  #pragma unroll
  for (int k = 0; k < 32; ++k) {
    int o = (k << 8) + t;             // o = c*512 + cell  == Af index
    int c = o >> 9, cell = o & 511;
    int lr = cell >> TCL2, lc = cell & ((1 << TCL2) - 1);
    float d = Df[cell];
    float val = (d > EPSF) ? (Af[o] / (d + EPSF)) : 1.0f;
    out[obase + (((size_t)c) << 18) + ((size_t)(row0 + lr) << 9) + (col0 + lc)] = val;
  }
}

// ================= fallback tier 2: global channel-last atomics =================
__global__ __launch_bounds__(256) void scatter_cl(const float* __restrict__ x,
                                                  const float* __restrict__ grid,
                                                  float* __restrict__ A,
                                                  float* __restrict__ D) {
  int tid = blockIdx.x * 256 + threadIdx.x;
  int b = tid >> 18, ij = tid & (HW - 1);
  float gi, gj; int ii0, jj0;
  coords(((const float2*)grid)[tid], gi, gj, ii0, jj0);
  float fi = gi - (float)ii0, fj = gj - (float)jj0;
  float wi[2] = {1.0f - fi, fi}, wj[2] = {1.0f - fj, fj};
  float xv[16];
  const float* xb = x + (((size_t)b * C_) << 18) + ij;
  #pragma unroll
  for (int c = 0; c < 16; ++c) xv[c] = xb[(size_t)c << 18];
  #pragma unroll
  for (int di = 0; di < 2; ++di) {
    int r = ii0 + di - 1;
    if ((unsigned)r >= (unsigned)H_) continue;
    #pragma unroll
    for (int dj = 0; dj < 2; ++dj) {
      int cc = jj0 + dj - 1;
      if ((unsigned)cc >= (unsigned)W_) continue;
      float wgt = wi[di] * wj[dj];
      int cell = (b << 18) + (r << 9) + cc;
      unsafeAtomicAdd(D + cell, wgt);
      float* Ab = A + ((size_t)cell << 4);
      #pragma unroll
      for (int c = 0; c < 16; ++c) unsafeAtomicAdd(Ab + c, xv[c] * wgt);
    }
  }
}

__global__ __launch_bounds__(256) void norm_transpose(const float* __restrict__ A,
                                                      const float* __restrict__ D,
                                                      float* __restrict__ out) {
  __shared__ float tile[64 * 17];
  __shared__ float dv[64];
  int t = threadIdx.x;
  int cellBase = blockIdx.x << 6;
  float4 v = ((const float4*)A)[(((size_t)cellBase) << 2) + t];
  int e = t << 2, cell = e >> 4, c0 = e & 15;
  tile[cell * 17 + c0 + 0] = v.x;
  tile[cell * 17 + c0 + 1] = v.y;
  tile[cell * 17 + c0 + 2] = v.z;
  tile[cell * 17 + c0 + 3] = v.w;
  if (t < 64) dv[t] = D[cellBase + t];
  __syncthreads();
  int b = cellBase >> 18, rem = cellBase & (HW - 1);
  #pragma unroll
  for (int k = 0; k < 4; ++k) {
    int o = t + (k << 8);
    int c = o >> 6, ce = o & 63;
    float a = tile[ce * 17 + c];
    float Dv = dv[ce];
    out[(((size_t)(b * C_ + c)) << 18) + rem + ce] = (Dv > EPSF) ? (a / (Dv + EPSF)) : 1.0f;
  }
}

// ================= fallback tier 3: direct =================
__global__ __launch_bounds__(256) void scatter_direct(const float* __restrict__ x,
                                                      const float* __restrict__ grid,
                                                      float* __restrict__ out,
                                                      float* __restrict__ D) {
  int tid = blockIdx.x * 256 + threadIdx.x;
  int b = tid >> 18, ij = tid & (HW - 1);
  float gi, gj; int ii0, jj0;
  coords(((const float2*)grid)[tid], gi, gj, ii0, jj0);
  float fi = gi - (float)ii0, fj = gj - (float)jj0;
  float wi[2] = {1.0f - fi, fi}, wj[2] = {1.0f - fj, fj};
  float xv[16];
  const float* xb = x + (((size_t)b * C_) << 18) + ij;
  #pragma unroll
  for (int c = 0; c < 16; ++c) xv[c] = xb[(size_t)c << 18];
  #pragma unroll
  for (int di = 0; di < 2; ++di) {
    int r = ii0 + di - 1;
    if ((unsigned)r >= (unsigned)H_) continue;
    #pragma unroll
    for (int dj = 0; dj < 2; ++dj) {
      int cc = jj0 + dj - 1;
      if ((unsigned)cc >= (unsigned)W_) continue;
      float wgt = wi[di] * wj[dj];
      int rcc = (r << 9) + cc;
      unsafeAtomicAdd(D + (b << 18) + rcc, wgt);
      #pragma unroll
      for (int c = 0; c < 16; ++c)
        unsafeAtomicAdd(out + (((size_t)(b * C_ + c)) << 18) + rcc, xv[c] * wgt);
    }
  }
}

__global__ __launch_bounds__(256) void norm_direct(float* __restrict__ out,
                                                   const float* __restrict__ D) {
  int n4 = B_ * C_ * HW / 4;
  int stride = gridDim.x * blockDim.x;
  for (int i4 = blockIdx.x * blockDim.x + threadIdx.x; i4 < n4; i4 += stride) {
    int base = i4 << 2;
    int b = base >> 22, rem = base & (HW - 1);
    float4 a = ((float4*)out)[i4];
    float4 dv = ((const float4*)D)[((b << 18) + rem) >> 2];
    float4 r;
    r.x = (dv.x > EPSF) ? (a.x / (dv.x + EPSF)) : 1.0f;
    r.y = (dv.y > EPSF) ? (a.y / (dv.y + EPSF)) : 1.0f;
    r.z = (dv.z > EPSF) ? (a.z / (dv.z + EPSF)) : 1.0f;
    r.w = (dv.w > EPSF) ? (a.w / (dv.w + EPSF)) : 1.0f;
    ((float4*)out)[i4] = r;
  }
}

extern "C" void kernel_launch(void* const* d_in, const int* in_sizes, int n_in,
                              void* d_out, int out_size, void* d_ws, size_t ws_size,
                              hipStream_t stream) {
  const float* x    = (const float*)d_in[0];
  const float* grid = (const float*)d_in[1];
  float* out = (float*)d_out;

  const size_t xclB  = (size_t)NPTS * C_ * sizeof(float);   // 64 MiB
  const size_t recB  = (size_t)CAP * 16;                    // 24 MiB
  const size_t binB  = (size_t)NBIN * sizeof(int);          // 8 KiB
  const size_t need1 = xclB + recB + 3 * binB;

  const size_t needD = (size_t)B_ * HW * sizeof(float);
  const size_t needA = (size_t)B_ * HW * C_ * sizeof(float);

  if (ws_size >= need1) {
    float*  x_cl   = (float*)d_ws;
    float4* recs   = (float4*)((char*)d_ws + xclB);
    int*    hist   = (int*)((char*)d_ws + xclB + recB);
    int*    offs   = hist + NBIN;
    int*    cursor = offs + NBIN;
    hipMemsetAsync(hist, 0, binB, stream);
    transpose_cl<<<NPTS / 64, 256, 0, stream>>>(x, x_cl);
    hist_kernel<<<512, 256, 0, stream>>>((const float2*)grid, hist);
    scan_bins<<<1, 256, 0, stream>>>(hist, offs, cursor);
    scatter_recs<<<NPTS / 256, 256, 0, stream>>>((const float2*)grid, cursor, recs);
    accum_bins<<<NBIN, 256, 0, stream>>>(recs, offs, hist, x_cl, out);
  } else if (ws_size >= needD + needA) {
    float* D = (float*)d_ws;
    float* A = (float*)((char*)d_ws + needD);
    hipMemsetAsync(d_ws, 0, needD + needA, stream);
    scatter_cl<<<NPTS / 256, 256, 0, stream>>>(x, grid, A, D);
    norm_transpose<<<NPTS / 64, 256, 0, stream>>>(A, D, out);
  } else {
    float* D = (float*)d_ws;
    hipMemsetAsync(out, 0, (size_t)B_ * C_ * HW * sizeof(float), stream);
    hipMemsetAsync(D, 0, needD, stream);
    scatter_direct<<<NPTS / 256, 256, 0, stream>>>(x, grid, out, D);
    norm_direct<<<2048, 256, 0, stream>>>(out, D);
  }
}

// Round 4
// 709.239 us; speedup vs baseline: 5.2332x; 1.0463x over previous
//
#include <hip/hip_runtime.h>

constexpr int B_ = 4, C_ = 16, H_ = 512, W_ = 512;
constexpr int HW = H_ * W_;            // 1<<18
constexpr int NPTS = B_ * HW;          // 1<<20
constexpr float EPSF = 1e-10f;

// tiles: 8 rows x 32 cols of output cells -> 256 cells, 4096 bins
constexpr int TRL2 = 3, TCL2 = 5;
constexpr int TROWS = H_ >> TRL2;      // 64
constexpr int TCOLS = W_ >> TCL2;      // 16
constexpr int NBIN  = B_ * TROWS * TCOLS;          // 4096
constexpr int CELLS = (1 << TRL2) * (1 << TCL2);   // 256
constexpr int PAD   = C_ + 1;          // 17: lane's channel atomics -> consecutive banks
constexpr int CAP   = 3 << 19;         // 1.57M records (expected ~1.22M)

// ---- shared coordinate math (identical in hist/scatter/accum) ----
__device__ __forceinline__ void coords(float2 g, float& gi, float& gj, int& ii0, int& jj0) {
  gi = fminf(fmaxf((g.x + 1.0f) * 0.5f * (float)H_ + 1.0f, 0.0f), (float)(H_ + 1 - 2e-10));
  gj = fminf(fmaxf((g.y + 1.0f) * 0.5f * (float)W_ + 1.0f, 0.0f), (float)(W_ + 1 - 2e-10));
  ii0 = (int)gi; jj0 = (int)gj;
}
__device__ __forceinline__ void tileR(int ii0, int& t0, int& t1, bool& v0, bool& v1) {
  int r0 = ii0 - 1, r1 = ii0;
  bool a = (unsigned)r0 < (unsigned)H_;
  bool b = (unsigned)r1 < (unsigned)H_;
  t0 = (a ? r0 : r1) >> TRL2;
  t1 = r1 >> TRL2;
  v0 = a | b;
  v1 = a & b & ((r1 >> TRL2) != (r0 >> TRL2));
}
__device__ __forceinline__ void tileC(int jj0, int& t0, int& t1, bool& v0, bool& v1) {
  int c0 = jj0 - 1, c1 = jj0;
  bool a = (unsigned)c0 < (unsigned)W_;
  bool b = (unsigned)c1 < (unsigned)W_;
  t0 = (a ? c0 : c1) >> TCL2;
  t1 = c1 >> TCL2;
  v0 = a | b;
  v1 = a & b & ((c1 >> TCL2) != (c0 >> TCL2));
}
__device__ __forceinline__ int binOf(int b, int tr, int tc) {
  return (b * TROWS + tr) * TCOLS + tc;
}

// ---- K0: BCHW -> channel-last x_cl[point][16] ----
__global__ __launch_bounds__(256) void transpose_cl(const float* __restrict__ x,
                                                    float* __restrict__ x_cl) {
  __shared__ float tile[64 * 17];
  int t = threadIdx.x;
  int cellBase = blockIdx.x << 6;          // 64 points per block
  int b   = cellBase >> 18;
  int ij0 = cellBase & (HW - 1);
  const float* xb = x + (((size_t)b * C_) << 18) + ij0;
  #pragma unroll
  for (int k = 0; k < 4; ++k) {
    int o = (k << 8) + t;
    int c = o >> 6, ce = o & 63;
    tile[ce * 17 + c] = xb[((size_t)c << 18) + ce];
  }
  __syncthreads();
  int cell = t >> 2, c0 = (t & 3) << 2;
  float4 v = { tile[cell * 17 + c0], tile[cell * 17 + c0 + 1],
               tile[cell * 17 + c0 + 2], tile[cell * 17 + c0 + 3] };
  ((float4*)x_cl)[(((size_t)cellBase) << 2) + t] = v;
}

// ---- K1: per-bin histogram (with tile-edge duplication) ----
__global__ __launch_bounds__(256) void hist_kernel(const float2* __restrict__ grid,
                                                   int* __restrict__ hist) {
  __shared__ int h[NBIN];                   // 16 KB
  for (int i = threadIdx.x; i < NBIN; i += 256) h[i] = 0;
  __syncthreads();
  int stride = gridDim.x * 256;
  for (int tid = blockIdx.x * 256 + threadIdx.x; tid < NPTS; tid += stride) {
    int b = tid >> 18;
    float gi, gj; int ii0, jj0;
    coords(grid[tid], gi, gj, ii0, jj0);
    int tr0, tr1, tc0, tc1; bool vr0, vr1, vc0, vc1;
    tileR(ii0, tr0, tr1, vr0, vr1);
    tileC(jj0, tc0, tc1, vc0, vc1);
    if (vr0 & vc0) atomicAdd(&h[binOf(b, tr0, tc0)], 1);
    if (vr0 & vc1) atomicAdd(&h[binOf(b, tr0, tc1)], 1);
    if (vr1 & vc0) atomicAdd(&h[binOf(b, tr1, tc0)], 1);
    if (vr1 & vc1) atomicAdd(&h[binOf(b, tr1, tc1)], 1);
  }
  __syncthreads();
  for (int i = threadIdx.x; i < NBIN; i += 256) { int v = h[i]; if (v) atomicAdd(&hist[i], v); }
}

// ---- K2: exclusive scan of 4096 bins, one block ----
__global__ __launch_bounds__(256) void scan_bins(const int* __restrict__ hist,
                                                 int* __restrict__ offs,
                                                 int* __restrict__ cursor) {
  __shared__ int part[256];
  int t = threadIdx.x;
  int base = t * 16;
  int loc[16]; int s = 0;
  #pragma unroll
  for (int i = 0; i < 16; ++i) { loc[i] = s; s += hist[base + i]; }
  part[t] = s;
  __syncthreads();
  for (int d = 1; d < 256; d <<= 1) {
    int v = part[t];
    int u = (t >= d) ? part[t - d] : 0;
    __syncthreads();
    part[t] = v + u;
    __syncthreads();
  }
  int tex = (t == 0) ? 0 : part[t - 1];
  #pragma unroll
  for (int i = 0; i < 16; ++i) { int o = tex + loc[i]; offs[base + i] = o; cursor[base + i] = o; }
}

// ---- K3: scatter 16B records {gi, gj, id} into bin segments ----
__global__ __launch_bounds__(256) void scatter_recs(const float2* __restrict__ grid,
                                                    int* __restrict__ cursor,
                                                    float4* __restrict__ recs) {
  int tid = blockIdx.x * 256 + threadIdx.x;
  if (tid >= NPTS) return;
  int b = tid >> 18;
  float gi, gj; int ii0, jj0;
  coords(grid[tid], gi, gj, ii0, jj0);
  int tr0, tr1, tc0, tc1; bool vr0, vr1, vc0, vc1;
  tileR(ii0, tr0, tr1, vr0, vr1);
  tileC(jj0, tc0, tc1, vc0, vc1);
  float4 rec = { gi, gj, __int_as_float(tid), 0.0f };
  if (vr0 & vc0) { int p = atomicAdd(&cursor[binOf(b, tr0, tc0)], 1); if (p < CAP) recs[p] = rec; }
  if (vr0 & vc1) { int p = atomicAdd(&cursor[binOf(b, tr0, tc1)], 1); if (p < CAP) recs[p] = rec; }
  if (vr1 & vc0) { int p = atomicAdd(&cursor[binOf(b, tr1, tc0)], 1); if (p < CAP) recs[p] = rec; }
  if (vr1 & vc1) { int p = atomicAdd(&cursor[binOf(b, tr1, tc1)], 1); if (p < CAP) recs[p] = rec; }
}

// ---- K4: per-tile LDS accumulate (native ds_add_f32) + normalize + BCHW write ----
__global__ __launch_bounds__(256) void accum_bins(const float4* __restrict__ recs,
                                                  const int* __restrict__ offs,
                                                  const int* __restrict__ hist,
                                                  const float* __restrict__ x_cl,
                                                  float* __restrict__ out) {
  __shared__ float Af[CELLS * PAD];  // [cell][17] -> lane's 16 ch-atomics hit consecutive banks
  __shared__ float Df[CELLS];
  int t = threadIdx.x;
  int bin = blockIdx.x;
  for (int i = t; i < CELLS * PAD; i += 256) Af[i] = 0.0f;
  for (int i = t; i < CELLS; i += 256) Df[i] = 0.0f;
  __syncthreads();

  int b   = bin >> 10;                         // / (TROWS*TCOLS)
  int trv = (bin >> 4) & (TROWS - 1);
  int tcv = bin & (TCOLS - 1);
  int row0 = trv << TRL2, col0 = tcv << TCL2;
  int start = offs[bin], cnt = hist[bin];

  for (int p = start + t; p < start + cnt; p += 256) {
    float4 rec = recs[p];
    float gi = rec.x, gj = rec.y;
    int id = __float_as_int(rec.z);
    int ii0 = (int)gi, jj0 = (int)gj;
    float fi = gi - (float)ii0, fj = gj - (float)jj0;
    float wr[2] = {1.0f - fi, fi};
    float wc[2] = {1.0f - fj, fj};
    const float4* xp = (const float4*)(x_cl + ((size_t)id << 4));
    float4 a0 = xp[0], a1 = xp[1], a2 = xp[2], a3 = xp[3];
    float xv[16] = { a0.x, a0.y, a0.z, a0.w, a1.x, a1.y, a1.z, a1.w,
                     a2.x, a2.y, a2.z, a2.w, a3.x, a3.y, a3.z, a3.w };
    #pragma unroll
    for (int di = 0; di < 2; ++di) {
      int r = ii0 - 1 + di;
      unsigned lr = (unsigned)(r - row0);
      if (lr >= (unsigned)(1 << TRL2)) continue;
      #pragma unroll
      for (int dj = 0; dj < 2; ++dj) {
        int cc = jj0 - 1 + dj;
        unsigned lc = (unsigned)(cc - col0);
        if (lc >= (unsigned)(1 << TCL2)) continue;
        float w = wr[di] * wc[dj];
        int cell = (int)(lr << TCL2) + (int)lc;
        float* Ab = &Af[cell * PAD];
        unsafeAtomicAdd(&Df[cell], w);
        #pragma unroll
        for (int c = 0; c < 16; ++c)
          unsafeAtomicAdd(Ab + c, xv[c] * w);   // ds_add_f32, consecutive banks
      }
    }
  }
  __syncthreads();

  size_t obase = ((size_t)b) << 22;   // b * C * HW
  #pragma unroll
  for (int k = 0; k < 16; ++k) {
    int o = (k << 8) + t;             // o = c*256 + cell
    int c = o >> 8, cell = o & 255;
    int lr = cell >> TCL2, lc = cell & ((1 << TCL2) - 1);
    float d = Df[cell];
    float val = (d > EPSF) ? (Af[cell * PAD + c] / (d + EPSF)) : 1.0f;
    out[obase + (((size_t)c) << 18) + ((size_t)(row0 + lr) << 9) + (col0 + lc)] = val;
  }
}

// ================= fallback tier 2: global channel-last atomics =================
__global__ __launch_bounds__(256) void scatter_cl(const float* __restrict__ x,
                                                  const float* __restrict__ grid,
                                                  float* __restrict__ A,
                                                  float* __restrict__ D) {
  int tid = blockIdx.x * 256 + threadIdx.x;
  int b = tid >> 18, ij = tid & (HW - 1);
  float gi, gj; int ii0, jj0;
  coords(((const float2*)grid)[tid], gi, gj, ii0, jj0);
  float fi = gi - (float)ii0, fj = gj - (float)jj0;
  float wi[2] = {1.0f - fi, fi}, wj[2] = {1.0f - fj, fj};
  float xv[16];
  const float* xb = x + (((size_t)b * C_) << 18) + ij;
  #pragma unroll
  for (int c = 0; c < 16; ++c) xv[c] = xb[(size_t)c << 18];
  #pragma unroll
  for (int di = 0; di < 2; ++di) {
    int r = ii0 + di - 1;
    if ((unsigned)r >= (unsigned)H_) continue;
    #pragma unroll
    for (int dj = 0; dj < 2; ++dj) {
      int cc = jj0 + dj - 1;
      if ((unsigned)cc >= (unsigned)W_) continue;
      float wgt = wi[di] * wj[dj];
      int cell = (b << 18) + (r << 9) + cc;
      unsafeAtomicAdd(D + cell, wgt);
      float* Ab = A + ((size_t)cell << 4);
      #pragma unroll
      for (int c = 0; c < 16; ++c) unsafeAtomicAdd(Ab + c, xv[c] * wgt);
    }
  }
}

__global__ __launch_bounds__(256) void norm_transpose(const float* __restrict__ A,
                                                      const float* __restrict__ D,
                                                      float* __restrict__ out) {
  __shared__ float tile[64 * 17];
  __shared__ float dv[64];
  int t = threadIdx.x;
  int cellBase = blockIdx.x << 6;
  float4 v = ((const float4*)A)[(((size_t)cellBase) << 2) + t];
  int e = t << 2, cell = e >> 4, c0 = e & 15;
  tile[cell * 17 + c0 + 0] = v.x;
  tile[cell * 17 + c0 + 1] = v.y;
  tile[cell * 17 + c0 + 2] = v.z;
  tile[cell * 17 + c0 + 3] = v.w;
  if (t < 64) dv[t] = D[cellBase + t];
  __syncthreads();
  int b = cellBase >> 18, rem = cellBase & (HW - 1);
  #pragma unroll
  for (int k = 0; k < 4; ++k) {
    int o = t + (k << 8);
    int c = o >> 6, ce = o & 63;
    float a = tile[ce * 17 + c];
    float Dv = dv[ce];
    out[(((size_t)(b * C_ + c)) << 18) + rem + ce] = (Dv > EPSF) ? (a / (Dv + EPSF)) : 1.0f;
  }
}

// ================= fallback tier 3: direct =================
__global__ __launch_bounds__(256) void scatter_direct(const float* __restrict__ x,
                                                      const float* __restrict__ grid,
                                                      float* __restrict__ out,
                                                      float* __restrict__ D) {
  int tid = blockIdx.x * 256 + threadIdx.x;
  int b = tid >> 18, ij = tid & (HW - 1);
  float gi, gj; int ii0, jj0;
  coords(((const float2*)grid)[tid], gi, gj, ii0, jj0);
  float fi = gi - (float)ii0, fj = gj - (float)jj0;
  float wi[2] = {1.0f - fi, fi}, wj[2] = {1.0f - fj, fj};
  float xv[16];
  const float* xb = x + (((size_t)b * C_) << 18) + ij;
  #pragma unroll
  for (int c = 0; c < 16; ++c) xv[c] = xb[(size_t)c << 18];
  #pragma unroll
  for (int di = 0; di < 2; ++di) {
    int r = ii0 + di - 1;
    if ((unsigned)r >= (unsigned)H_) continue;
    #pragma unroll
    for (int dj = 0; dj < 2; ++dj) {
      int cc = jj0 + dj - 1;
      if ((unsigned)cc >= (unsigned)W_) continue;
      float wgt = wi[di] * wj[dj];
      int rcc = (r << 9) + cc;
      unsafeAtomicAdd(D + (b << 18) + rcc, wgt);
      #pragma unroll
      for (int c = 0; c < 16; ++c)
        unsafeAtomicAdd(out + (((size_t)(b * C_ + c)) << 18) + rcc, xv[c] * wgt);
    }
  }
}

__global__ __launch_bounds__(256) void norm_direct(float* __restrict__ out,
                                                   const float* __restrict__ D) {
  int n4 = B_ * C_ * HW / 4;
  int stride = gridDim.x * blockDim.x;
  for (int i4 = blockIdx.x * blockDim.x + threadIdx.x; i4 < n4; i4 += stride) {
    int base = i4 << 2;
    int b = base >> 22, rem = base & (HW - 1);
    float4 a = ((float4*)out)[i4];
    float4 dv = ((const float4*)D)[((b << 18) + rem) >> 2];
    float4 r;
    r.x = (dv.x > EPSF) ? (a.x / (dv.x + EPSF)) : 1.0f;
    r.y = (dv.y > EPSF) ? (a.y / (dv.y + EPSF)) : 1.0f;
    r.z = (dv.z > EPSF) ? (a.z / (dv.z + EPSF)) : 1.0f;
    r.w = (dv.w > EPSF) ? (a.w / (dv.w + EPSF)) : 1.0f;
    ((float4*)out)[i4] = r;
  }
}

extern "C" void kernel_launch(void* const* d_in, const int* in_sizes, int n_in,
                              void* d_out, int out_size, void* d_ws, size_t ws_size,
                              hipStream_t stream) {
  const float* x    = (const float*)d_in[0];
  const float* grid = (const float*)d_in[1];
  float* out = (float*)d_out;

  const size_t xclB  = (size_t)NPTS * C_ * sizeof(float);   // 64 MiB
  const size_t recB  = (size_t)CAP * 16;                    // 24 MiB
  const size_t binB  = (size_t)NBIN * sizeof(int);          // 16 KiB
  const size_t need1 = xclB + recB + 3 * binB;

  const size_t needD = (size_t)B_ * HW * sizeof(float);
  const size_t needA = (size_t)B_ * HW * C_ * sizeof(float);

  if (ws_size >= need1) {
    float*  x_cl   = (float*)d_ws;
    float4* recs   = (float4*)((char*)d_ws + xclB);
    int*    hist   = (int*)((char*)d_ws + xclB + recB);
    int*    offs   = hist + NBIN;
    int*    cursor = offs + NBIN;
    hipMemsetAsync(hist, 0, binB, stream);
    transpose_cl<<<NPTS / 64, 256, 0, stream>>>(x, x_cl);
    hist_kernel<<<512, 256, 0, stream>>>((const float2*)grid, hist);
    scan_bins<<<1, 256, 0, stream>>>(hist, offs, cursor);
    scatter_recs<<<NPTS / 256, 256, 0, stream>>>((const float2*)grid, cursor, recs);
    accum_bins<<<NBIN, 256, 0, stream>>>(recs, offs, hist, x_cl, out);
  } else if (ws_size >= needD + needA) {
    float* D = (float*)d_ws;
    float* A = (float*)((char*)d_ws + needD);
    hipMemsetAsync(d_ws, 0, needD + needA, stream);
    scatter_cl<<<NPTS / 256, 256, 0, stream>>>(x, grid, A, D);
    norm_transpose<<<NPTS / 64, 256, 0, stream>>>(A, D, out);
  } else {
    float* D = (float*)d_ws;
    hipMemsetAsync(out, 0, (size_t)B_ * C_ * HW * sizeof(float), stream);
    hipMemsetAsync(D, 0, needD, stream);
    scatter_direct<<<NPTS / 256, 256, 0, stream>>>(x, grid, out, D);
    norm_direct<<<2048, 256, 0, stream>>>(out, D);
  }
}